// Round 3
// baseline (352.976 us; speedup 1.0000x reference)
//
#include <hip/hip_runtime.h>

#define BB 4
#define CC 256
#define HH 96
#define WW 128
#define PP 9
#define OFF 4
#define CSPLIT 4         // channel splits across blocks (reduce via atomicAdd)
#define CPB (CC / CSPLIT)  // 64 channels per block
#define CCH 8            // channels per LDS chunk
#define NPAIR (CCH / 2)  // 4 f16x2 channel pairs per chunk
#define TPB 288          // 9 dy * 32 pixel-groups

typedef _Float16 h2 __attribute__((ext_vector_type(2)));

__device__ __forceinline__ h2 u2h(unsigned u) { union { unsigned u; h2 h; } x; x.u = u; return x.h; }

#if __has_builtin(__builtin_amdgcn_fdot2)
__device__ __forceinline__ float dot2(h2 a, h2 b, float c) { return __builtin_amdgcn_fdot2(a, b, c, false); }
#else
__device__ __forceinline__ float dot2(h2 a, h2 b, float c) { return c + (float)a[0] * (float)b[0] + (float)a[1] * (float)b[1]; }
#endif

__device__ __forceinline__ unsigned pk(float a, float b) {
#if __has_builtin(__builtin_amdgcn_cvt_pkrtz)
  auto r = __builtin_amdgcn_cvt_pkrtz(a, b);
  unsigned u;
  __builtin_memcpy(&u, &r, 4);
  return u;
#else
  h2 h; h[0] = (_Float16)a; h[1] = (_Float16)b;
  unsigned u;
  __builtin_memcpy(&u, &h, 4);
  return u;
#endif
}

__global__ __launch_bounds__(TPB, 4) void corr_kernel(const float* __restrict__ in1,
                                                      const float* __restrict__ in2,
                                                      float* __restrict__ out) {
  // in2 halo tile: 4 pairs x 9 rows x (4 pad + 128 + 4 pad) cols of f16x2
  __shared__ unsigned s2[NPAIR][PP][136];  // 19584 B
  __shared__ unsigned s1[NPAIR][WW];       // 2048 B  -> 21.6 KB total, 7 blocks/CU LDS cap

  // XCD-aware swizzle: contiguous h-band per XCD so in2 row re-reads hit L2.
  const int bx = blockIdx.x;
  const int xcd = bx & 7;
  const int slot = bx >> 3;            // 0..191
  const int csplit = slot & 3;         // 0..3
  const int s2i = slot >> 2;           // 0..47
  const int b = s2i / 12;              // 0..3
  const int h = xcd * 12 + (s2i % 12); // 0..95
  const int cbase = csplit * CPB;

  const int tid = threadIdx.x;
  const int dy = tid >> 5;             // 0..8
  const int pxg = tid & 31;            // 0..31
  const int x0 = pxg << 2;             // 4 consecutive output pixels

  // Zero LDS once: column pads and out-of-range rows stay zero forever.
  for (int i = tid; i < NPAIR * PP * 136; i += TPB) ((unsigned*)s2)[i] = 0u;
  __syncthreads();

  float acc[4][PP];
#pragma unroll
  for (int px = 0; px < 4; ++px)
#pragma unroll
    for (int dx = 0; dx < PP; ++dx) acc[px][dx] = 0.f;

  const int plane = HH * WW;           // 12288
  const int base_b = b * CC * plane;

#pragma unroll 1
  for (int cc = 0; cc < CPB; cc += CCH) {
    const int c0 = cbase + cc;
    // ---- stage in2 chunk: units (r, p, col-pair): 9*4*64 = 2304 = 8*TPB
#pragma unroll 4
    for (int i = tid; i < PP * NPAIR * 64; i += TPB) {
      const int r = i >> 8;            // /(NPAIR*64)
      const int p = (i >> 6) & (NPAIR - 1);
      const int col = (i & 63) << 1;
      const int hr = h + r - OFF;
      if (hr >= 0 && hr < HH) {
        const float* g = in2 + base_b + (c0 + 2 * p) * plane + hr * WW + col;
        const float2 a = *(const float2*)g;
        const float2 c = *(const float2*)(g + plane);  // next channel
        *(uint2*)&s2[p][r][col + 4] = make_uint2(pk(a.x, c.x), pk(a.y, c.y));
      }
    }
    // ---- stage in1 chunk: units (p, col-pair): 4*64 = 256
    for (int i = tid; i < NPAIR * 64; i += TPB) {
      const int p = i >> 6;
      const int col = (i & 63) << 1;
      const float* g = in1 + base_b + (c0 + 2 * p) * plane + h * WW + col;
      const float2 a = *(const float2*)g;
      const float2 c = *(const float2*)(g + plane);
      *(uint2*)&s1[p][col] = make_uint2(pk(a.x, c.x), pk(a.y, c.y));
    }
    __syncthreads();

    // ---- compute: sliding 12-wide f16x2 window, 36 accumulators
#pragma unroll
    for (int p = 0; p < NPAIR; ++p) {
      unsigned q[4];
      unsigned w[12];
      *(uint4*)q = *(const uint4*)&s1[p][x0];
      const uint4* wp = (const uint4*)&s2[p][dy][x0];
      *(uint4*)(w + 0) = wp[0];
      *(uint4*)(w + 4) = wp[1];
      *(uint4*)(w + 8) = wp[2];
#pragma unroll
      for (int px = 0; px < 4; ++px)
#pragma unroll
        for (int dx = 0; dx < PP; ++dx)
          acc[px][dx] = dot2(u2h(w[px + dx]), u2h(q[px]), acc[px][dx]);
    }
    __syncthreads();
  }

  // ---- epilogue: atomic accumulate (4 c-split blocks per output element)
  const int ob = (b * PP + dy) * PP * plane + h * WW + x0;
#pragma unroll
  for (int dx = 0; dx < PP; ++dx) {
    float* o = out + ob + dx * plane;
#pragma unroll
    for (int px = 0; px < 4; ++px) atomicAdd(o + px, acc[px][dx]);
  }
}

extern "C" void kernel_launch(void* const* d_in, const int* in_sizes, int n_in,
                              void* d_out, int out_size, void* d_ws, size_t ws_size,
                              hipStream_t stream) {
  const float* in1 = (const float*)d_in[0];
  const float* in2 = (const float*)d_in[1];
  float* out = (float*)d_out;
  // d_out is poisoned before each call; atomics need zeros.
  hipMemsetAsync(d_out, 0, (size_t)out_size * sizeof(float), stream);
  // 1536 blocks = 4 b * 96 h * 4 c-splits (xcd-swizzled), 288 thr = 9 dy * 32 pxg
  corr_kernel<<<dim3(BB * HH * CSPLIT), dim3(TPB), 0, stream>>>(in1, in2, out);
}

// Round 4
// 251.003 us; speedup vs baseline: 1.4063x; 1.4063x over previous
//
#include <hip/hip_runtime.h>

#define BB 4
#define CC 256
#define HH 96
#define WW 128
#define PP 9
#define OFF 4
#define CCH 16           // channels per LDS chunk
#define NPAIR (CCH / 2)  // 8 f16x2 channel pairs per chunk
#define TPB 288          // 9 dy * 32 pixel-groups
#define TW 72            // staged in2 tile width (f16x2 cols), 69 used
#define XCOLS 64         // output columns per block

typedef _Float16 h2 __attribute__((ext_vector_type(2)));

__device__ __forceinline__ h2 u2h(unsigned u) { union { unsigned u; h2 h; } x; x.u = u; return x.h; }

#if __has_builtin(__builtin_amdgcn_fdot2)
__device__ __forceinline__ float dot2(h2 a, h2 b, float c) { return __builtin_amdgcn_fdot2(a, b, c, false); }
#else
__device__ __forceinline__ float dot2(h2 a, h2 b, float c) { return c + (float)a[0] * (float)b[0] + (float)a[1] * (float)b[1]; }
#endif

__device__ __forceinline__ unsigned pk(float a, float b) {
#if __has_builtin(__builtin_amdgcn_cvt_pkrtz)
  auto r = __builtin_amdgcn_cvt_pkrtz(a, b);
  unsigned u;
  __builtin_memcpy(&u, &r, 4);
  return u;
#else
  h2 h; h[0] = (_Float16)a; h[1] = (_Float16)b;
  unsigned u;
  __builtin_memcpy(&u, &h, 4);
  return u;
#endif
}

// Grid: 1536 = 4b * 96h * 2 x-halves * 2 dx-halves -> exactly 6 blocks/CU,
// 27 waves/CU. No cross-block reduction (output-space split only).
__global__ __launch_bounds__(TPB, 7) void corr_kernel(const float* __restrict__ in1,
                                                      const float* __restrict__ in2,
                                                      float* __restrict__ out) {
  __shared__ unsigned s2[NPAIR][PP][TW];   // 20736 B, fully rewritten every chunk
  __shared__ unsigned s1[NPAIR][XCOLS];    // 2048 B   -> 22.8 KB, 7-block LDS cap

  // XCD swizzle: h-band per XCD; sibling blocks (same b,h) share xcd -> L2 hits
  const int bx = blockIdx.x;
  const int xcd = bx & 7;
  const int slot = bx >> 3;            // 0..191
  const int dxh = slot & 1;            // 0: dx 0..4, 1: dx 5..8
  const int xh = (slot >> 1) & 1;      // x half
  const int s3 = slot >> 2;            // 0..47
  const int b = s3 / 12;
  const int h = xcd * 12 + (s3 % 12);
  const int xbase = xh * XCOLS;
  const int sh = dxh ? (xbase + 1) : (xbase - OFF);  // global x = sh + lds_col
  const int dxbase = dxh * 5;
  const int KD = dxh ? 4 : 5;          // stored offsets (both halves compute 5)

  const int tid = threadIdx.x;
  const int dy = tid >> 5;             // 0..8
  const int pxg = tid & 31;            // 0..31
  const int L0 = pxg << 1;             // thread's 2 output pixels: lds cols L0,L0+1

  // staging decomposition: per row-iteration, 288 units = 8 pairs * 36 col-pairs
  const int sp = tid / 36;             // pair 0..7 (uniform across chunk loop)
  const int sc2 = tid - sp * 36;       // col-pair 0..35
  const int sL = sc2 << 1;
  const int sgx = sh + sL;             // global x of staged col pair

  float acc[2][5];
#pragma unroll
  for (int px = 0; px < 2; ++px)
#pragma unroll
    for (int k = 0; k < 5; ++k) acc[px][k] = 0.f;

  const int plane = HH * WW;           // 12288
  const int base_b = b * CC * plane;

#pragma unroll 1
  for (int c0 = 0; c0 < CC; c0 += CCH) {
    // ---- stage in2 tile: 9 rows, each row = one full 288-unit sweep
#pragma unroll
    for (int r = 0; r < PP; ++r) {
      const int hr = h + r - OFF;
      float a0 = 0.f, a1 = 0.f, b0 = 0.f, b1 = 0.f;
      if (hr >= 0 && hr < HH) {
        const float* g = in2 + base_b + (c0 + 2 * sp) * plane + hr * WW;
        if (sgx >= 0 && sgx + 1 < WW) {
          const float2 va = *(const float2*)(g + sgx);
          const float2 vb = *(const float2*)(g + plane + sgx);
          a0 = va.x; a1 = va.y; b0 = vb.x; b1 = vb.y;
        } else {
          if (sgx >= 0 && sgx < WW) { a0 = g[sgx]; b0 = g[plane + sgx]; }
          if (sgx + 1 >= 0 && sgx + 1 < WW) { a1 = g[sgx + 1]; b1 = g[plane + sgx + 1]; }
        }
      }
      *(uint2*)&s2[sp][r][sL] = make_uint2(pk(a0, b0), pk(a1, b1));
    }
    // ---- stage in1: 256 units = 8 pairs * 32 col-pairs (always in range)
    if (tid < NPAIR * 32) {
      const int p = tid >> 5;
      const int c2 = tid & 31;
      const float* g = in1 + base_b + (c0 + 2 * p) * plane + h * WW + xbase + (c2 << 1);
      const float2 va = *(const float2*)g;
      const float2 vb = *(const float2*)(g + plane);
      *(uint2*)&s1[p][c2 << 1] = make_uint2(pk(va.x, vb.x), pk(va.y, vb.y));
    }
    __syncthreads();

    // ---- compute: 6-wide f16x2 window, 10 dot2 per pair
#pragma unroll
    for (int p = 0; p < NPAIR; ++p) {
      unsigned q[2], w[6];
      *(uint2*)q = *(const uint2*)&s1[p][L0];
      *(uint2*)&w[0] = *(const uint2*)&s2[p][dy][L0];
      *(uint2*)&w[2] = *(const uint2*)&s2[p][dy][L0 + 2];
      *(uint2*)&w[4] = *(const uint2*)&s2[p][dy][L0 + 4];
#pragma unroll
      for (int px = 0; px < 2; ++px)
#pragma unroll
        for (int k = 0; k < 5; ++k)
          acc[px][k] = dot2(u2h(w[px + k]), u2h(q[px]), acc[px][k]);
    }
    __syncthreads();
  }

  // ---- epilogue: float2 per stored offset, coalesced across pxg
  const int gx0 = xbase + L0;
#pragma unroll
  for (int k = 0; k < 5; ++k) {
    if (k < KD) {
      float* o = out + ((b * PP + dy) * PP + dxbase + k) * plane + h * WW + gx0;
      *(float2*)o = make_float2(acc[0][k], acc[1][k]);
    }
  }
}

extern "C" void kernel_launch(void* const* d_in, const int* in_sizes, int n_in,
                              void* d_out, int out_size, void* d_ws, size_t ws_size,
                              hipStream_t stream) {
  const float* in1 = (const float*)d_in[0];
  const float* in2 = (const float*)d_in[1];
  float* out = (float*)d_out;
  // 1536 blocks = 4b * 96h * 2xh * 2dxh (xcd-swizzled), 288 thr = 9dy * 32pxg
  corr_kernel<<<dim3(BB * HH * 4), dim3(TPB), 0, stream>>>(in1, in2, out);
}

// Round 5
// 160.707 us; speedup vs baseline: 2.1964x; 1.5619x over previous
//
#include <hip/hip_runtime.h>

#define BB 4
#define CC 256
#define HH 96
#define WW 128
#define PP 9
#define OFF 4
#define CCH 16           // channels per chunk
#define NPAIR (CCH / 2)  // 8 f16x2 channel pairs per chunk
#define NCH (CC / CCH)   // 16 chunks
#define TPB 288          // 9 dy * 32 pixel-groups
#define TW 72            // staged in2 cols (64 out + 8 halo)
#define XCOLS 64         // output columns per block

typedef _Float16 h2 __attribute__((ext_vector_type(2)));

__device__ __forceinline__ h2 u2h(unsigned u) { union { unsigned u; h2 h; } x; x.u = u; return x.h; }

#if __has_builtin(__builtin_amdgcn_fdot2)
__device__ __forceinline__ float dot2(h2 a, h2 b, float c) { return __builtin_amdgcn_fdot2(a, b, c, false); }
#else
__device__ __forceinline__ float dot2(h2 a, h2 b, float c) { return c + (float)a[0] * (float)b[0] + (float)a[1] * (float)b[1]; }
#endif

__device__ __forceinline__ unsigned pk(float a, float b) {
#if __has_builtin(__builtin_amdgcn_cvt_pkrtz)
  auto r = __builtin_amdgcn_cvt_pkrtz(a, b);
  unsigned u; __builtin_memcpy(&u, &r, 4); return u;
#else
  h2 h; h[0] = (_Float16)a; h[1] = (_Float16)b;
  unsigned u; __builtin_memcpy(&u, &h, 4); return u;
#endif
}

// 768 blocks = 4b * 96h * 2xh = exactly 3 blocks/CU (no tail imbalance).
// Software-pipelined: global loads for chunk c+1 issued before compute of
// chunk c; the vmcnt(0) drain at the end-of-compute barrier is hidden.
__global__ __launch_bounds__(TPB, 4) void corr_kernel(const float* __restrict__ in1,
                                                      const float* __restrict__ in2,
                                                      float* __restrict__ out) {
  __shared__ unsigned s2[NPAIR][PP][TW];   // 20736 B
  __shared__ unsigned s1[NPAIR][XCOLS];    // 2048 B -> 22.8 KB total

  // XCD swizzle: 12-row h-band per XCD so the 9-row dy-halo stays in-XCD L2.
  const int bx = blockIdx.x;
  const int xcd = bx & 7;
  const int slot = bx >> 3;            // 0..95
  const int xh = slot & 1;
  const int s3 = slot >> 1;            // 0..47
  const int b = s3 / 12;
  const int h = xcd * 12 + (s3 % 12);
  const int xbase = xh * XCOLS;

  const int tid = threadIdx.x;
  const int dy = tid >> 5;             // 0..8
  const int pxg = tid & 31;            // 0..31
  const int L0 = pxg << 1;             // 2 output px -> lds cols L0, L0+1

  // staging role: 288 = 8 pairs * 36 col-pairs; col pairs are edge-aligned
  // (OOB pairs are fully OOB), so validity is a single per-lane bool.
  const int sp = tid / 36;             // channel pair 0..7
  const int sc2 = tid - sp * 36;       // col-pair 0..35
  const int sL = sc2 << 1;
  const int sgx = xbase - OFF + sL;    // global x of staged pair (even)
  const bool colv = (sgx >= 0) && (sgx < WW);
  // row validity is block-uniform (scalar branches only)
  const int rlo = (h >= OFF) ? 0 : (OFF - h);
  const int rhi = (PP < HH + OFF - h) ? PP : (HH + OFF - h);

  const int plane = HH * WW;           // 12288
  const long base_b = (long)b * CC * plane;

  // hoisted base pointers (advance by CCH*plane per chunk)
  const float* p2a = in2 + base_b + (long)(2 * sp) * plane + (long)(h - OFF) * WW + sgx;
  const float* p2b = p2a + plane;
  const int i1p = tid >> 5, i1c = tid & 31;  // in1 role (tid<256)
  const float* p1a = in1 + base_b + (long)(2 * i1p) * plane + h * WW + xbase + (i1c << 1);
  const float* p1b = p1a + plane;

  // pre-zero s2 once: OOB rows/cols never written afterwards
  for (int i = tid; i < NPAIR * PP * TW; i += TPB) ((unsigned*)s2)[i] = 0u;

  float acc[2][PP];
#pragma unroll
  for (int px = 0; px < 2; ++px)
#pragma unroll
    for (int dx = 0; dx < PP; ++dx) acc[px][dx] = 0.f;

  // prefetch registers
  float2 fa[PP], fb[PP], ga, gb;

  // ---- prefetch chunk 0
  if (colv) {
#pragma unroll
    for (int r = 0; r < PP; ++r)
      if (r >= rlo && r < rhi) {
        fa[r] = *(const float2*)(p2a + r * WW);
        fb[r] = *(const float2*)(p2b + r * WW);
      }
  }
  if (tid < NPAIR * 32) { ga = *(const float2*)p1a; gb = *(const float2*)p1b; }
  __syncthreads();  // covers the pre-zero

#pragma unroll 1
  for (int c = 0; c < NCH; ++c) {
    // ---- store phase: pk prefetched regs -> LDS
    if (colv) {
#pragma unroll
      for (int r = 0; r < PP; ++r)
        if (r >= rlo && r < rhi)
          *(uint2*)&s2[sp][r][sL] = make_uint2(pk(fa[r].x, fb[r].x), pk(fa[r].y, fb[r].y));
    }
    if (tid < NPAIR * 32)
      *(uint2*)&s1[i1p][i1c << 1] = make_uint2(pk(ga.x, gb.x), pk(ga.y, gb.y));
    __syncthreads();  // A: LDS visible

    // ---- prefetch chunk c+1 (in flight during compute)
    if (c + 1 < NCH) {
      const long adv = (long)(c + 1) * CCH * plane;
      if (colv) {
#pragma unroll
        for (int r = 0; r < PP; ++r)
          if (r >= rlo && r < rhi) {
            fa[r] = *(const float2*)(p2a + adv + r * WW);
            fb[r] = *(const float2*)(p2b + adv + r * WW);
          }
      }
      if (tid < NPAIR * 32) { ga = *(const float2*)(p1a + adv); gb = *(const float2*)(p1b + adv); }
    }

    // ---- compute chunk c: 2px x 9dx sliding f16x2 window
#pragma unroll
    for (int p = 0; p < NPAIR; ++p) {
      unsigned q[2], w[10];
      *(uint2*)q = *(const uint2*)&s1[p][L0];
#pragma unroll
      for (int i = 0; i < 5; ++i)
        *(uint2*)&w[2 * i] = *(const uint2*)&s2[p][dy][L0 + 2 * i];
#pragma unroll
      for (int px = 0; px < 2; ++px)
#pragma unroll
        for (int dx = 0; dx < PP; ++dx)
          acc[px][dx] = dot2(u2h(w[px + dx]), u2h(q[px]), acc[px][dx]);
    }
    __syncthreads();  // B: reads done; vmcnt drain lands after compute
  }

  // ---- epilogue: 9 coalesced float2 stores
  const int gx0 = xbase + L0;
  float* ob = out + ((long)(b * PP + dy) * PP) * plane + h * WW + gx0;
#pragma unroll
  for (int dx = 0; dx < PP; ++dx)
    *(float2*)(ob + (long)dx * plane) = make_float2(acc[0][dx], acc[1][dx]);
}

extern "C" void kernel_launch(void* const* d_in, const int* in_sizes, int n_in,
                              void* d_out, int out_size, void* d_ws, size_t ws_size,
                              hipStream_t stream) {
  const float* in1 = (const float*)d_in[0];
  const float* in2 = (const float*)d_in[1];
  float* out = (float*)d_out;
  // 768 blocks = 4b * 96h * 2xh (xcd-swizzled), 288 thr = 9dy * 32pxg
  corr_kernel<<<dim3(BB * HH * 2), dim3(TPB), 0, stream>>>(in1, in2, out);
}